// Round 1
// baseline (2049.069 us; speedup 1.0000x reference)
//
#include <hip/hip_runtime.h>
#include <math.h>

// Problem constants (from setup_inputs: 64 graphs x 512 nodes, K=16 -> K+1=17,
// RBF=128 channels, radius=8).
#define NPG   512        // nodes per graph
#define KK    17         // K+1 neighbors (incl. self)
#define RBFN  128
#define SPLIT 4          // blocks per graph for the kNN kernel
#define THR1  (NPG / SPLIT)

// ---------------------------------------------------------------------------
// Kernel 1: per-target-node kNN (top-17 smallest squared distances, stable
// tie-break by ascending source index, matching jax.lax.top_k).
// Writes: src (as float) to out[0..E), dst to out[E..2E), raw dist to the
// mask slot out[130E..131E) (temporary; kernel 3 converts it to 0/1).
// One thread per target node; per-graph positions staged in LDS (broadcast
// reads across the wave -> conflict-free).
// Distance arithmetic uses _rn intrinsics (no fma contraction) so d2 matches
// the numpy reference bit-exactly -> identical neighbor ordering.
// ---------------------------------------------------------------------------
__global__ __launch_bounds__(THR1) void knn_kernel(const float* __restrict__ pos,
                                                   float* __restrict__ out,
                                                   int E) {
  __shared__ float xs[NPG], ys[NPG], zs[NPG];
  const int g = blockIdx.x / SPLIT;
  const int part = blockIdx.x % SPLIT;
  const float* gp = pos + (size_t)g * NPG * 3;
  for (int i = threadIdx.x; i < NPG; i += THR1) {
    xs[i] = gp[i * 3 + 0];
    ys[i] = gp[i * 3 + 1];
    zs[i] = gp[i * 3 + 2];
  }
  __syncthreads();

  const int t = part * THR1 + threadIdx.x;
  const float px = xs[t], py = ys[t], pz = zs[t];

  // top-17 sorted ascending by d2; ties keep earlier source index first.
  float bd[KK];
  int bi[KK];
#pragma unroll
  for (int k = 0; k < KK; ++k) { bd[k] = INFINITY; bi[k] = 0; }

  for (int j = 0; j < NPG; ++j) {
    float dx = __fsub_rn(px, xs[j]);
    float dy = __fsub_rn(py, ys[j]);
    float dz = __fsub_rn(pz, zs[j]);
    float d2 = __fadd_rn(__fadd_rn(__fmul_rn(dx, dx), __fmul_rn(dy, dy)),
                         __fmul_rn(dz, dz));
    if (d2 < bd[KK - 1]) {            // strict <: equal d2 keeps earlier j
      bd[KK - 1] = d2;
      bi[KK - 1] = j;
      // one bubble pass restores sorted order (array was sorted before).
      // All indices compile-time constant after unroll -> stays in VGPRs.
#pragma unroll
      for (int k = KK - 1; k >= 1; --k) {
        bool sw = bd[k] < bd[k - 1];  // strict <: stable for ties
        float tv = sw ? bd[k - 1] : bd[k];
        int   ti = sw ? bi[k - 1] : bi[k];
        bd[k - 1] = sw ? bd[k] : bd[k - 1];
        bi[k - 1] = sw ? bi[k] : bi[k - 1];
        bd[k] = tv;
        bi[k] = ti;
      }
    }
  }

  const int node = g * NPG + t;
  const size_t ebase = (size_t)node * KK;
  float* __restrict__ srcp = out;                       // [E]
  float* __restrict__ dstp = out + (size_t)E;           // [E]
  float* __restrict__ dtmp = out + (size_t)130 * E;     // mask slot as temp dist
#pragma unroll
  for (int k = 0; k < KK; ++k) {
    srcp[ebase + k] = (float)(bi[k] + g * NPG);
    dstp[ebase + k] = (float)node;
    dtmp[ebase + k] = __fsqrt_rn(fmaxf(bd[k], 1e-12f));
  }
}

// ---------------------------------------------------------------------------
// Kernel 2: Gaussian RBF embedding. One thread per (edge, channel); writes
// fully coalesced. This is the HBM-write-bound phase (285 MB).
// ---------------------------------------------------------------------------
__global__ __launch_bounds__(256) void rbf_kernel(const float* __restrict__ dtmp,
                                                  const float* __restrict__ bias,
                                                  float* __restrict__ repr,
                                                  long long total) {
  const float step = 8.0f / 127.0f;            // offsets[1]-offsets[0] in f32
  const float coeff = -0.5f / (step * step);
  const long long stride = (long long)gridDim.x * blockDim.x;
  for (long long i = (long long)blockIdx.x * blockDim.x + threadIdx.x; i < total;
       i += stride) {
    const int e = (int)(i >> 7);
    const int c = (int)(i & (RBFN - 1));
    const float dist = dtmp[e];                // broadcast across 128 threads
    const float offc = (float)c * step;
    const float dif = __fsub_rn(dist, offc);
    float v = __expf(coeff * dif * dif) + bias[c];
    repr[i] = (dist <= 8.0f) ? v : 0.0f;       // radius mask zeroes the row
  }
}

// ---------------------------------------------------------------------------
// Kernel 3: convert the raw distances parked in the mask slot into the 0/1
// mask, in place (same thread reads then writes the same element).
// ---------------------------------------------------------------------------
__global__ __launch_bounds__(256) void mask_kernel(float* __restrict__ maskp, int E) {
  const int i = blockIdx.x * blockDim.x + threadIdx.x;
  if (i < E) {
    const float d = maskp[i];
    maskp[i] = (d <= 8.0f) ? 1.0f : 0.0f;
  }
}

extern "C" void kernel_launch(void* const* d_in, const int* in_sizes, int n_in,
                              void* d_out, int out_size, void* d_ws, size_t ws_size,
                              hipStream_t stream) {
  const float* pos = (const float*)d_in[0];
  const float* bias = (const float*)d_in[1];
  (void)n_in; (void)d_ws; (void)ws_size; (void)out_size;

  const int N = in_sizes[0] / 3;   // 32768 nodes
  const int B = N / NPG;           // 64 graphs
  const int E = N * KK;            // 557056 edges
  float* out = (float*)d_out;

  // 1) kNN: indices, dst, raw dist (into mask slot).
  knn_kernel<<<B * SPLIT, THR1, 0, stream>>>(pos, out, E);

  // 2) RBF embedding (writes edge_repr, out[2E .. 2E+128E)).
  const long long total = (long long)E * RBFN;
  rbf_kernel<<<2048, 256, 0, stream>>>(out + (size_t)130 * E, bias,
                                       out + (size_t)2 * E, total);

  // 3) dist -> 0/1 mask in place.
  mask_kernel<<<(E + 255) / 256, 256, 0, stream>>>(out + (size_t)130 * E, E);
}

// Round 2
// 216.225 us; speedup vs baseline: 9.4765x; 9.4765x over previous
//
#include <hip/hip_runtime.h>
#include <math.h>

// 64 graphs x 512 nodes, K+1=17 neighbors (incl self), 128 RBF channels, r=8.
#define NPG   512
#define KK    17
#define RBFN  128
#define THR1  128
#define SPLIT (NPG / THR1)   // 4 blocks per graph

typedef unsigned long long u64;

// ---------------------------------------------------------------------------
// Kernel 1: per-target kNN. Top-17 state held in 17 NAMED u64 registers
// (key = d2_bits<<32 | j : IEEE bits of d2>=0 are order-monotonic, low word
// breaks ties by ascending j exactly like lax.top_k). Branch-free
// compare-exchange insertion chain: each candidate's key bubbles to its slot,
// the previous max falls off the end. No arrays -> no scratch (R1 post-mortem:
// VGPR_Count=24 proved bd[]/bi[] were in scratch, ~9.5K cyc/candidate).
// Distances use _rn intrinsics (no fma contraction) to match numpy bit-exact.
// ---------------------------------------------------------------------------
__global__ __launch_bounds__(THR1) void knn_kernel(const float* __restrict__ pos,
                                                   float* __restrict__ out,
                                                   int E) {
  __shared__ float xs[NPG], ys[NPG], zs[NPG];
  const int g = blockIdx.x / SPLIT;
  const int part = blockIdx.x % SPLIT;
  const float* gp = pos + (size_t)g * NPG * 3;
  for (int i = threadIdx.x; i < NPG; i += THR1) {
    xs[i] = gp[i * 3 + 0];
    ys[i] = gp[i * 3 + 1];
    zs[i] = gp[i * 3 + 2];
  }
  __syncthreads();

  const int t = part * THR1 + threadIdx.x;
  const float px = xs[t], py = ys[t], pz = zs[t];

  const u64 SENT = 0xFFFFFFFFFFFFFFFFull;
  u64 b0 = SENT, b1 = SENT, b2 = SENT, b3 = SENT, b4 = SENT, b5 = SENT,
      b6 = SENT, b7 = SENT, b8 = SENT, b9 = SENT, b10 = SENT, b11 = SENT,
      b12 = SENT, b13 = SENT, b14 = SENT, b15 = SENT, b16 = SENT;

// compare-exchange: slot keeps min, key carries max onward (stable: strict <)
#define CE(B)                              \
  {                                        \
    const bool lt = key < (B);             \
    const u64 mn = lt ? key : (B);         \
    const u64 mx = lt ? (B) : key;         \
    (B) = mn;                              \
    key = mx;                              \
  }

  for (int j = 0; j < NPG; ++j) {
    const float dx = __fsub_rn(px, xs[j]);
    const float dy = __fsub_rn(py, ys[j]);
    const float dz = __fsub_rn(pz, zs[j]);
    const float d2 = __fadd_rn(__fadd_rn(__fmul_rn(dx, dx), __fmul_rn(dy, dy)),
                               __fmul_rn(dz, dz));
    u64 key = ((u64)__float_as_uint(d2) << 32) | (unsigned)j;
    CE(b0) CE(b1) CE(b2) CE(b3) CE(b4) CE(b5) CE(b6) CE(b7) CE(b8)
    CE(b9) CE(b10) CE(b11) CE(b12) CE(b13) CE(b14) CE(b15) CE(b16)
  }
#undef CE

  const int node = g * NPG + t;
  const size_t ebase = (size_t)node * KK;
  float* __restrict__ srcp = out;                    // [E]
  float* __restrict__ dstp = out + (size_t)E;        // [E]
  float* __restrict__ dtmp = out + (size_t)130 * E;  // mask slot as temp dist

#define EMIT(B, Kk)                                                         \
  {                                                                         \
    const float d2v = __uint_as_float((unsigned)((B) >> 32));               \
    const int jv = (int)((B) & 0xFFFFFFFFu);                                \
    srcp[ebase + (Kk)] = (float)(jv + g * NPG);                             \
    dstp[ebase + (Kk)] = (float)node;                                       \
    dtmp[ebase + (Kk)] = __fsqrt_rn(fmaxf(d2v, 1e-12f));                    \
  }
  EMIT(b0, 0) EMIT(b1, 1) EMIT(b2, 2) EMIT(b3, 3) EMIT(b4, 4) EMIT(b5, 5)
  EMIT(b6, 6) EMIT(b7, 7) EMIT(b8, 8) EMIT(b9, 9) EMIT(b10, 10)
  EMIT(b11, 11) EMIT(b12, 12) EMIT(b13, 13) EMIT(b14, 14) EMIT(b15, 15)
  EMIT(b16, 16)
#undef EMIT
}

// ---------------------------------------------------------------------------
// Kernel 2: Gaussian RBF embedding, float4 stores (16B/lane). HBM-write-bound
// phase: 285 MB -> ~45us floor.
// ---------------------------------------------------------------------------
__global__ __launch_bounds__(256) void rbf_kernel(const float* __restrict__ dtmp,
                                                  const float* __restrict__ bias,
                                                  float* __restrict__ repr,
                                                  long long total4) {
  const float step = 8.0f / 127.0f;
  const float coeff = -0.5f / (step * step);
  const long long stride = (long long)gridDim.x * blockDim.x;
  for (long long i = (long long)blockIdx.x * blockDim.x + threadIdx.x;
       i < total4; i += stride) {
    const int e = (int)(i >> 5);            // 32 float4-groups per edge
    const int c0 = ((int)i & 31) * 4;       // first channel of this group
    const float dist = dtmp[e];             // broadcast across 32 threads
    const bool ok = dist <= 8.0f;
    const float4 bv = *reinterpret_cast<const float4*>(bias + c0);
    float4 o;
    {
      const float dif = __fsub_rn(dist, (float)(c0 + 0) * step);
      o.x = ok ? (__expf(coeff * dif * dif) + bv.x) : 0.0f;
    }
    {
      const float dif = __fsub_rn(dist, (float)(c0 + 1) * step);
      o.y = ok ? (__expf(coeff * dif * dif) + bv.y) : 0.0f;
    }
    {
      const float dif = __fsub_rn(dist, (float)(c0 + 2) * step);
      o.z = ok ? (__expf(coeff * dif * dif) + bv.z) : 0.0f;
    }
    {
      const float dif = __fsub_rn(dist, (float)(c0 + 3) * step);
      o.w = ok ? (__expf(coeff * dif * dif) + bv.w) : 0.0f;
    }
    *reinterpret_cast<float4*>(repr + i * 4) = o;
  }
}

// ---------------------------------------------------------------------------
// Kernel 3: raw distances (parked in mask slot) -> 0/1 mask, in place.
// ---------------------------------------------------------------------------
__global__ __launch_bounds__(256) void mask_kernel(float* __restrict__ maskp, int E) {
  const int i = blockIdx.x * blockDim.x + threadIdx.x;
  if (i < E) {
    const float d = maskp[i];
    maskp[i] = (d <= 8.0f) ? 1.0f : 0.0f;
  }
}

extern "C" void kernel_launch(void* const* d_in, const int* in_sizes, int n_in,
                              void* d_out, int out_size, void* d_ws, size_t ws_size,
                              hipStream_t stream) {
  const float* pos = (const float*)d_in[0];
  const float* bias = (const float*)d_in[1];
  (void)n_in; (void)d_ws; (void)ws_size; (void)out_size;

  const int N = in_sizes[0] / 3;  // 32768 nodes
  const int B = N / NPG;          // 64 graphs
  const int E = N * KK;           // 557056 edges
  float* out = (float*)d_out;

  // 1) kNN: src/dst indices + raw dist (into mask slot).
  knn_kernel<<<B * SPLIT, THR1, 0, stream>>>(pos, out, E);

  // 2) RBF embedding -> out[2E .. 2E+128E), float4 per thread.
  const long long total4 = (long long)E * (RBFN / 4);
  rbf_kernel<<<4096, 256, 0, stream>>>(out + (size_t)130 * E, bias,
                                       out + (size_t)2 * E, total4);

  // 3) dist -> 0/1 mask in place.
  mask_kernel<<<(E + 255) / 256, 256, 0, stream>>>(out + (size_t)130 * E, E);
}

// Round 3
// 85.019 us; speedup vs baseline: 24.1012x; 2.5432x over previous
//
#include <hip/hip_runtime.h>
#include <math.h>

// 64 graphs x 512 nodes, K+1=17 neighbors (incl self), 128 RBF channels, r=8.
#define NPG   512
#define KK    17
#define RBFN  128
#define SC    4                  // scanners per target
#define TPB   256                // threads per knn block
#define TGT_PER_BLK (TPB / SC)   // 64 targets per block

// ---------------------------------------------------------------------------
// kNN kernel. Key encoding: key = (double)float_bits(d2) * 512 + j.
//  - d2 >= 0 so IEEE bits are order-monotonic; bits <= 2^31 so (double)bits
//    is exact; *512 + j (j<512) stays < 2^41 -> exact -> total order with
//    stable ascending-j tie-break, identical to jax.lax.top_k.
//  - compare-exchange = v_min_f64 + v_max_f64: 2 instr vs 5 for u64 (R2
//    post-mortem: chain issue-count + 2 waves/CU made knn latency-bound).
// 4 scanners per target (j = 4*jj+q) -> 8 waves/CU; each scanner keeps a
// sorted top-17 in 17 NAMED doubles (registers), dumps to LDS; scanner q==0
// does a branchless 4-pointer merge and emits outputs.
// ---------------------------------------------------------------------------
__global__ __launch_bounds__(TPB, 2) void knn_kernel(const float* __restrict__ pos,
                                                     float* __restrict__ out,
                                                     int E) {
  __shared__ float xs[NPG], ys[NPG], zs[NPG];
  __shared__ double keys[TPB][KK + 1];  // +1 pad slot = +INF sentinel
  const int bpg = NPG / TGT_PER_BLK;    // 8 blocks per graph
  const int g = blockIdx.x / bpg;
  const int part = blockIdx.x % bpg;
  const float* gp = pos + (size_t)g * NPG * 3;
  for (int i = threadIdx.x; i < NPG; i += TPB) {
    xs[i] = gp[i * 3 + 0];
    ys[i] = gp[i * 3 + 1];
    zs[i] = gp[i * 3 + 2];
  }
  __syncthreads();

  const int q = threadIdx.x & (SC - 1);
  const int tl = threadIdx.x >> 2;
  const int t = part * TGT_PER_BLK + tl;
  const float px = xs[t], py = ys[t], pz = zs[t];

  const double INF = __builtin_inf();
  double b0 = INF, b1 = INF, b2 = INF, b3 = INF, b4 = INF, b5 = INF, b6 = INF,
         b7 = INF, b8 = INF, b9 = INF, b10 = INF, b11 = INF, b12 = INF,
         b13 = INF, b14 = INF, b15 = INF, b16 = INF;

#define CE(B)                                  \
  {                                            \
    const double mn_ = fmin(key, (B));         \
    const double mx_ = fmax(key, (B));         \
    (B) = mn_;                                 \
    key = mx_;                                 \
  }

  double jd = (double)q;           // tracks (double)j exactly
  for (int jj = 0; jj < NPG / SC; ++jj) {
    const int j = (jj << 2) | q;
    const float dx = __fsub_rn(px, xs[j]);
    const float dy = __fsub_rn(py, ys[j]);
    const float dz = __fsub_rn(pz, zs[j]);
    const float d2 = __fadd_rn(__fadd_rn(__fmul_rn(dx, dx), __fmul_rn(dy, dy)),
                               __fmul_rn(dz, dz));
    double key = fma((double)__float_as_uint(d2), 512.0, jd);
    jd += 4.0;
    CE(b0) CE(b1) CE(b2) CE(b3) CE(b4) CE(b5) CE(b6) CE(b7) CE(b8)
    CE(b9) CE(b10) CE(b11) CE(b12) CE(b13) CE(b14) CE(b15) CE(b16)
  }
#undef CE

  // dump sorted list (ascending) + sentinel pad
  double* myk = keys[threadIdx.x];
  myk[0] = b0;  myk[1] = b1;  myk[2] = b2;  myk[3] = b3;  myk[4] = b4;
  myk[5] = b5;  myk[6] = b6;  myk[7] = b7;  myk[8] = b8;  myk[9] = b9;
  myk[10] = b10; myk[11] = b11; myk[12] = b12; myk[13] = b13; myk[14] = b14;
  myk[15] = b15; myk[16] = b16; myk[17] = INF;
  __syncthreads();

  if (q == 0) {
    const double* L0 = keys[tl * 4 + 0];
    const double* L1 = keys[tl * 4 + 1];
    const double* L2 = keys[tl * 4 + 2];
    const double* L3 = keys[tl * 4 + 3];
    int i0 = 0, i1 = 0, i2 = 0, i3 = 0;
    double h0 = L0[0], h1 = L1[0], h2 = L2[0], h3 = L3[0];

    const int node = g * NPG + t;
    const int goff = g * NPG;
    const size_t ebase = (size_t)node * KK;
    float* __restrict__ srcp = out;                    // [E]
    float* __restrict__ dstp = out + (size_t)E;        // [E]
    float* __restrict__ dtmp = out + (size_t)130 * E;  // mask slot: raw dist

    for (int k = 0; k < KK; ++k) {
      const double mn = fmin(fmin(h0, h1), fmin(h2, h3));
      // decode: key = bits*512 + j, both exact
      const unsigned bits = (unsigned)(mn * 0.001953125);  // 1/512
      const unsigned jv = (unsigned)(mn - (double)bits * 512.0);
      const float d2v = __uint_as_float(bits);
      const float dv = __fsqrt_rn(fmaxf(d2v, 1e-12f));
      srcp[ebase + k] = (float)(jv + goff);
      dstp[ebase + k] = (float)node;
      dtmp[ebase + k] = dv;
      // branchless advance (keys unique -> exactly one head equals mn;
      // pad slot is +INF and never emitted since >=17 real keys remain)
      const bool a0 = (h0 == mn), a1 = (h1 == mn), a2 = (h2 == mn),
                 a3 = (h3 == mn);
      i0 += a0; i1 += a1; i2 += a2; i3 += a3;
      h0 = a0 ? L0[i0] : h0;
      h1 = a1 ? L1[i1] : h1;
      h2 = a2 ? L2[i2] : h2;
      h3 = a3 ? L3[i3] : h3;
    }
  }
}

// ---------------------------------------------------------------------------
// RBF embedding, float4 stores. Reads raw dist from the mask slot; lane
// (i&31)==0 overwrites it with the 0/1 mask AFTER its 32-group (same wave,
// program order) has loaded dist -> race-free, eliminates the 3rd kernel.
// ---------------------------------------------------------------------------
__global__ __launch_bounds__(256) void rbf_kernel(const float* __restrict__ bias,
                                                  float* __restrict__ out,
                                                  int E, long long total4) {
  float* __restrict__ dtmp = out + (size_t)130 * E;  // dist in, mask out
  float* __restrict__ repr = out + (size_t)2 * E;
  const float step = 8.0f / 127.0f;
  const float coeff = -0.5f / (step * step);
  const long long stride = (long long)gridDim.x * blockDim.x;
  for (long long i = (long long)blockIdx.x * blockDim.x + threadIdx.x;
       i < total4; i += stride) {
    const int e = (int)(i >> 5);        // 32 float4-groups per edge
    const int c0 = ((int)i & 31) * 4;   // first channel of this group
    const float dist = dtmp[e];         // broadcast across the 32-group
    const bool ok = dist <= 8.0f;
    const float4 bv = *reinterpret_cast<const float4*>(bias + c0);
    float4 o;
    {
      const float dif = __fsub_rn(dist, (float)(c0 + 0) * step);
      o.x = ok ? (__expf(coeff * dif * dif) + bv.x) : 0.0f;
    }
    {
      const float dif = __fsub_rn(dist, (float)(c0 + 1) * step);
      o.y = ok ? (__expf(coeff * dif * dif) + bv.y) : 0.0f;
    }
    {
      const float dif = __fsub_rn(dist, (float)(c0 + 2) * step);
      o.z = ok ? (__expf(coeff * dif * dif) + bv.z) : 0.0f;
    }
    {
      const float dif = __fsub_rn(dist, (float)(c0 + 3) * step);
      o.w = ok ? (__expf(coeff * dif * dif) + bv.w) : 0.0f;
    }
    *reinterpret_cast<float4*>(repr + i * 4) = o;
    if (((int)i & 31) == 0) dtmp[e] = ok ? 1.0f : 0.0f;  // after group's loads
  }
}

extern "C" void kernel_launch(void* const* d_in, const int* in_sizes, int n_in,
                              void* d_out, int out_size, void* d_ws, size_t ws_size,
                              hipStream_t stream) {
  const float* pos = (const float*)d_in[0];
  const float* bias = (const float*)d_in[1];
  (void)n_in; (void)d_ws; (void)ws_size; (void)out_size;

  const int N = in_sizes[0] / 3;  // 32768 nodes
  const int B = N / NPG;          // 64 graphs
  const int E = N * KK;           // 557056 edges
  float* out = (float*)d_out;

  // 1) kNN: src/dst indices + raw dist (into mask slot).
  knn_kernel<<<B * (NPG / TGT_PER_BLK), TPB, 0, stream>>>(pos, out, E);

  // 2) RBF embedding + in-place dist->mask conversion.
  const long long total4 = (long long)E * (RBFN / 4);
  rbf_kernel<<<4096, 256, 0, stream>>>(bias, out, E, total4);
}